// Round 1
// baseline (186.521 us; speedup 1.0000x reference)
//
#include <hip/hip_runtime.h>
#include <hip/hip_bf16.h>
#include <stdint.h>

#define B_ 8
#define S_ 1024
#define NH_ 16
#define D_ 64
#define H_ 1024
#define M_TOT (B_*S_)

typedef __attribute__((ext_vector_type(8))) short short8;
typedef __attribute__((ext_vector_type(4))) float f32x4;

static __device__ __forceinline__ unsigned short f2bf(float f) {
  union { float f; unsigned u; } c; c.f = f;
  unsigned u = c.u;
  return (unsigned short)((u + 0x7fffu + ((u >> 16) & 1u)) >> 16);
}

static __device__ __forceinline__ void gld_lds16(void* lds, const void* g) {
  __builtin_amdgcn_global_load_lds((const __attribute__((address_space(1))) unsigned*)g,
                                   (__attribute__((address_space(3))) unsigned*)lds, 16, 0, 0);
}

// ---------------- kernel 1: f32 -> bf16 conversion (X and the 3 weights) ----
__global__ void cvt_f32_bf16(const float* __restrict__ X,
                             const float* __restrict__ Wq,
                             const float* __restrict__ Wk,
                             const float* __restrict__ Wv,
                             unsigned short* __restrict__ Xbf,
                             unsigned short* __restrict__ Wbf) {
  const long long NX = (long long)M_TOT * H_;
  const long long NW = (long long)H_ * H_;
  long long t = (long long)blockIdx.x * blockDim.x + threadIdx.x;
  const long long stride = (long long)gridDim.x * blockDim.x;
  const long long total4 = (NX + 3 * NW) >> 2;
  for (; t < total4; t += stride) {
    long long e = t << 2;
    const float* src; unsigned short* dst;
    if (e < NX) { src = X + e; dst = Xbf + e; }
    else {
      long long r = e - NX;
      int w = (int)(r / NW);
      long long o = r - (long long)w * NW;
      src = (w == 0 ? Wq : (w == 1 ? Wk : Wv)) + o;
      dst = Wbf + (long long)w * NW + o;
    }
    float4 v = *(const float4*)src;
    ushort4 u;
    u.x = f2bf(v.x); u.y = f2bf(v.y); u.z = f2bf(v.z); u.w = f2bf(v.w);
    *(ushort4*)dst = u;
  }
}

// ---------------- kernel 2: QKV projection GEMM ----------------------------
// C[m][n] = sum_k X[m][k] * W[n][k]  (+bias). z=0:Q (scaled 1/8, [b,h,s,d])
// z=1:K ([b,h,s,d]), z=2:V transposed ([b,h,d,s]) via swapped operand roles.
#define GBM 128
#define GBN 128
#define GBK 64

__global__ __launch_bounds__(256) void qkv_gemm(
    const unsigned short* __restrict__ Xbf,
    const unsigned short* __restrict__ Wbf,
    const float* __restrict__ bq, const float* __restrict__ bk,
    const float* __restrict__ bv,
    unsigned short* __restrict__ Qo, unsigned short* __restrict__ Ko,
    unsigned short* __restrict__ Vt) {
  __shared__ char lds[GBM * GBK * 2 * 2];   // A 16KB + B 16KB
  char* ldsA = lds;
  char* ldsB = lds + GBM * GBK * 2;

  const int tid = threadIdx.x;
  const int w = tid >> 6;
  const int l = tid & 63;
  const int z = blockIdx.z;
  const int mtile = blockIdx.x * GBM;
  const int ntile = blockIdx.y * GBN;
  const int wm = w >> 1, wn = w & 1;
  const int lrow = l & 15, lgrp = l >> 4;

  const unsigned short* Wz = Wbf + (long long)z * H_ * H_;

  f32x4 acc[4][4];
  f32x4 zero = {0.f, 0.f, 0.f, 0.f};
  #pragma unroll
  for (int i = 0; i < 4; ++i)
    #pragma unroll
    for (int j = 0; j < 4; ++j) acc[i][j] = zero;

  for (int kt = 0; kt < H_ / GBK; ++kt) {
    const int k0 = kt * GBK;
    // stage A+B tiles: LDS linear, global source pre-swizzled (slot ^ row&7)
    #pragma unroll
    for (int t = 0; t < 4; ++t) {
      int j = w * 4 + t;                       // 0..15, wave-uniform
      int row = j * 8 + (l >> 3);
      int so = ((l & 7) ^ (row & 7)) * 8;
      gld_lds16(ldsA + j * 1024, Xbf + (long long)(mtile + row) * H_ + k0 + so);
      gld_lds16(ldsB + j * 1024, Wz  + (long long)(ntile + row) * H_ + k0 + so);
    }
    __syncthreads();

    char* srcA = (z == 2) ? ldsB : ldsA;      // z==2: swap roles so C rows = d
    char* srcB = (z == 2) ? ldsA : ldsB;
    const int wA = (z == 2) ? wn : wm;
    const int wB = (z == 2) ? wm : wn;

    short8 af[4][2], bf[4][2];
    #pragma unroll
    for (int ib = 0; ib < 4; ++ib)
      #pragma unroll
      for (int ks = 0; ks < 2; ++ks) {
        int rA = wA * 64 + ib * 16 + lrow;
        af[ib][ks] = *(const short8*)(srcA + rA * 128 + (((ks * 4 + lgrp) ^ (rA & 7)) * 16));
        int rB = wB * 64 + ib * 16 + lrow;
        bf[ib][ks] = *(const short8*)(srcB + rB * 128 + (((ks * 4 + lgrp) ^ (rB & 7)) * 16));
      }
    #pragma unroll
    for (int ib = 0; ib < 4; ++ib)
      #pragma unroll
      for (int jb = 0; jb < 4; ++jb)
        #pragma unroll
        for (int ks = 0; ks < 2; ++ks)
          acc[ib][jb] = __builtin_amdgcn_mfma_f32_16x16x32_bf16(
              af[ib][ks], bf[jb][ks], acc[ib][jb], 0, 0, 0);
    __syncthreads();
  }

  const float* bias = (z == 0) ? bq : (z == 1) ? bk : bv;
  if (z != 2) {
    unsigned short* O = (z == 0) ? Qo : Ko;
    #pragma unroll
    for (int jb = 0; jb < 4; ++jb) {
      int n = ntile + wn * 64 + jb * 16 + lrow;
      float bv_ = bias[n];
      int h = n >> 6, d = n & 63;
      #pragma unroll
      for (int ib = 0; ib < 4; ++ib)
        #pragma unroll
        for (int r = 0; r < 4; ++r) {
          int m = mtile + wm * 64 + ib * 16 + lgrp * 4 + r;
          float val = acc[ib][jb][r] + bv_;
          if (z == 0) val *= 0.125f;           // fold 1/sqrt(64) into Q
          int b = m >> 10, s = m & 1023;
          O[(((long long)(b * NH_ + h)) * S_ + s) * D_ + d] = f2bf(val);
        }
    }
  } else {
    #pragma unroll
    for (int ib = 0; ib < 4; ++ib)
      #pragma unroll
      for (int r = 0; r < 4; ++r) {
        int n = ntile + wn * 64 + ib * 16 + lgrp * 4 + r;   // d-side (C row)
        float bv_ = bias[n];
        int h = n >> 6, d = n & 63;
        #pragma unroll
        for (int jb = 0; jb < 4; ++jb) {
          int m = mtile + wm * 64 + jb * 16 + lrow;          // s-side (C col)
          float val = acc[ib][jb][r] + bv_;
          int b = m >> 10, s = m & 1023;
          Vt[(((long long)(b * NH_ + h)) * D_ + d) * S_ + s] = f2bf(val);
        }
      }
  }
}

// ---------------- kernel 3: fused flash attention --------------------------
// grid (16 qtiles, 128 bh); block 256 = 4 waves; wave owns 16 q rows.
__global__ __launch_bounds__(256) void attn_fused(
    const unsigned short* __restrict__ Qbf,
    const unsigned short* __restrict__ Kbf,
    const unsigned short* __restrict__ Vtb,
    const float* __restrict__ mask,
    float* __restrict__ out) {
  __shared__ char lds[8192 * 2 + 4 * 2304];   // K 8KB | Vt 8KB | P 4x2304B
  char* ldsK = lds;
  char* ldsV = lds + 8192;
  const int tid = threadIdx.x, w = tid >> 6, l = tid & 63;
  char* ldsP = lds + 16384 + w * 2304;        // per-wave, 16 rows x 144B
  const int bh = blockIdx.y;
  const int b = bh >> 4;
  const int qt = blockIdx.x;
  const int lrow = l & 15, lgrp = l >> 4;

  // Q fragments (held in regs for the whole kernel)
  const int qrow = qt * 64 + w * 16 + lrow;
  const unsigned short* qptr = Qbf + ((long long)bh * S_ + qrow) * D_;
  short8 qf[2];
  qf[0] = *(const short8*)(qptr + lgrp * 8);
  qf[1] = *(const short8*)(qptr + 32 + lgrp * 8);

  const float* mrow = mask + b * S_;

  f32x4 acc[4];
  f32x4 zero = {0.f, 0.f, 0.f, 0.f};
  #pragma unroll
  for (int i = 0; i < 4; ++i) acc[i] = zero;
  float m_run[4] = {-1e30f, -1e30f, -1e30f, -1e30f};
  float l_run[4] = {0.f, 0.f, 0.f, 0.f};

  for (int kt = 0; kt < S_ / 64; ++kt) {
    const int key0 = kt * 64;
    // stage K tile [64 keys][64 d] and V^T tile [64 d][64 keys], swizzled src
    #pragma unroll
    for (int t = 0; t < 2; ++t) {
      int j = w * 2 + t;                        // 0..7, wave-uniform
      int row = j * 8 + (l >> 3);
      int so = ((l & 7) ^ (row & 7)) * 8;
      gld_lds16(ldsK + j * 1024, Kbf + ((long long)bh * S_ + key0 + row) * D_ + so);
      gld_lds16(ldsV + j * 1024, Vtb + ((long long)bh * D_ + row) * S_ + key0 + so);
    }
    __syncthreads();

    // S = Q K^T  (+mask), C frag: col=key=l&15, row=q=lgrp*4+r
    float sv[4][4];
    #pragma unroll
    for (int kb = 0; kb < 4; ++kb) {
      f32x4 t = zero;
      #pragma unroll
      for (int ks = 0; ks < 2; ++ks) {
        int kr = kb * 16 + lrow;
        short8 bfr = *(const short8*)(ldsK + kr * 128 + (((ks * 4 + lgrp) ^ (kr & 7)) * 16));
        t = __builtin_amdgcn_mfma_f32_16x16x32_bf16(qf[ks], bfr, t, 0, 0, 0);
      }
      float mv = mrow[key0 + kb * 16 + lrow];
      #pragma unroll
      for (int r = 0; r < 4; ++r) sv[kb][r] = t[r] + mv;
    }

    // online softmax over this 64-key block
    float resc[4];
    float pv[4][4];
    #pragma unroll
    for (int r = 0; r < 4; ++r) {
      float mx = fmaxf(fmaxf(sv[0][r], sv[1][r]), fmaxf(sv[2][r], sv[3][r]));
      #pragma unroll
      for (int off = 1; off < 16; off <<= 1) mx = fmaxf(mx, __shfl_xor(mx, off));
      float mn = fmaxf(m_run[r], mx);
      resc[r] = __expf(m_run[r] - mn);
      float ps = 0.f;
      #pragma unroll
      for (int kb = 0; kb < 4; ++kb) {
        float p = __expf(sv[kb][r] - mn);
        pv[kb][r] = p; ps += p;
      }
      #pragma unroll
      for (int off = 1; off < 16; off <<= 1) ps += __shfl_xor(ps, off);
      l_run[r] = l_run[r] * resc[r] + ps;
      m_run[r] = mn;
    }
    #pragma unroll
    for (int db = 0; db < 4; ++db) {
      f32x4 a = acc[db];
      #pragma unroll
      for (int r = 0; r < 4; ++r) a[r] *= resc[r];
      acc[db] = a;
    }

    // P -> per-wave LDS [16 q][64 key], stride 144B (bank-clean)
    #pragma unroll
    for (int kb = 0; kb < 4; ++kb)
      #pragma unroll
      for (int r = 0; r < 4; ++r)
        *(unsigned short*)(ldsP + (lgrp * 4 + r) * 144 + (kb * 16 + lrow) * 2) =
            f2bf(pv[kb][r]);
    asm volatile("s_waitcnt lgkmcnt(0)" ::: "memory");
    __builtin_amdgcn_sched_barrier(0);

    // ctx += P V : A frag from P lds (row=q=l&15, k=key), B frag from V^T lds
    short8 pa[2];
    #pragma unroll
    for (int ks = 0; ks < 2; ++ks)
      pa[ks] = *(const short8*)(ldsP + lrow * 144 + ks * 64 + lgrp * 16);
    #pragma unroll
    for (int db = 0; db < 4; ++db)
      #pragma unroll
      for (int ks = 0; ks < 2; ++ks) {
        int vr = db * 16 + lrow;
        short8 vb = *(const short8*)(ldsV + vr * 128 + (((ks * 4 + lgrp) ^ (vr & 7)) * 16));
        acc[db] = __builtin_amdgcn_mfma_f32_16x16x32_bf16(pa[ks], vb, acc[db], 0, 0, 0);
      }
    __syncthreads();
  }

  // epilogue: out[b, s, h*64+d] = acc / l_run
  const int h = bh & 15;
  #pragma unroll
  for (int db = 0; db < 4; ++db)
    #pragma unroll
    for (int r = 0; r < 4; ++r) {
      int srow = qt * 64 + w * 16 + lgrp * 4 + r;
      int dd = db * 16 + lrow;
      out[((long long)b * S_ + srow) * H_ + h * D_ + dd] = acc[db][r] / l_run[r];
    }
}

// ---------------- launcher -------------------------------------------------
extern "C" void kernel_launch(void* const* d_in, const int* in_sizes, int n_in,
                              void* d_out, int out_size, void* d_ws, size_t ws_size,
                              hipStream_t stream) {
  const float* X    = (const float*)d_in[0];
  const float* mask = (const float*)d_in[1];
  const float* Wq   = (const float*)d_in[2];
  const float* bq   = (const float*)d_in[3];
  const float* Wk   = (const float*)d_in[4];
  const float* bk   = (const float*)d_in[5];
  const float* Wv   = (const float*)d_in[6];
  const float* bv   = (const float*)d_in[7];
  float* out = (float*)d_out;

  char* ws = (char*)d_ws;
  unsigned short* Xbf = (unsigned short*)ws;                 // 16 MB
  unsigned short* Wbf = (unsigned short*)(ws + 16777216);    //  6 MB
  unsigned short* Qb  = (unsigned short*)(ws + 23068672);    // 16 MB
  unsigned short* Kb  = (unsigned short*)(ws + 39845888);    // 16 MB
  unsigned short* Vt  = (unsigned short*)(ws + 56623104);    // 16 MB (=73,400,320 total)

  hipLaunchKernelGGL(cvt_f32_bf16, dim3(2048), dim3(256), 0, stream,
                     X, Wq, Wk, Wv, Xbf, Wbf);
  hipLaunchKernelGGL(qkv_gemm, dim3(M_TOT / GBM, H_ / GBN, 3), dim3(256), 0, stream,
                     Xbf, Wbf, bq, bk, bv, Qb, Kb, Vt);
  hipLaunchKernelGGL(attn_fused, dim3(S_ / 64, B_ * NH_), dim3(256), 0, stream,
                     Qb, Kb, Vt, mask, out);
}

// Round 2
// 138.037 us; speedup vs baseline: 1.3512x; 1.3512x over previous
//
#include <hip/hip_runtime.h>
#include <hip/hip_bf16.h>
#include <stdint.h>

#define B_ 8
#define S_ 1024
#define NH_ 16
#define D_ 64
#define H_ 1024
#define M_TOT (B_*S_)
#define LOG2E 1.44269504088896f

typedef __attribute__((ext_vector_type(8))) short short8;
typedef __attribute__((ext_vector_type(4))) float f32x4;
typedef __attribute__((ext_vector_type(16))) float f32x16;

#if __has_builtin(__builtin_amdgcn_exp2f)
#define EXP2(x) __builtin_amdgcn_exp2f(x)
#else
#define EXP2(x) __expf((x) * 0.69314718056f)
#endif

static __device__ __forceinline__ unsigned short f2bf(float f) {
  union { float f; unsigned u; } c; c.f = f;
  unsigned u = c.u;
  return (unsigned short)((u + 0x7fffu + ((u >> 16) & 1u)) >> 16);
}

static __device__ __forceinline__ void gld_lds16(void* lds, const void* g) {
  __builtin_amdgcn_global_load_lds((const __attribute__((address_space(1))) unsigned*)g,
                                   (__attribute__((address_space(3))) unsigned*)lds, 16, 0, 0);
}

// ---------------- kernel 1: f32 -> bf16 conversion (X and the 3 weights) ----
__global__ void cvt_f32_bf16(const float* __restrict__ X,
                             const float* __restrict__ Wq,
                             const float* __restrict__ Wk,
                             const float* __restrict__ Wv,
                             unsigned short* __restrict__ Xbf,
                             unsigned short* __restrict__ Wbf) {
  const long long NX = (long long)M_TOT * H_;
  const long long NW = (long long)H_ * H_;
  long long t = (long long)blockIdx.x * blockDim.x + threadIdx.x;
  const long long stride = (long long)gridDim.x * blockDim.x;
  const long long total4 = (NX + 3 * NW) >> 2;
  for (; t < total4; t += stride) {
    long long e = t << 2;
    const float* src; unsigned short* dst;
    if (e < NX) { src = X + e; dst = Xbf + e; }
    else {
      long long r = e - NX;
      int w = (int)(r / NW);
      long long o = r - (long long)w * NW;
      src = (w == 0 ? Wq : (w == 1 ? Wk : Wv)) + o;
      dst = Wbf + (long long)w * NW + o;
    }
    float4 v = *(const float4*)src;
    ushort4 u;
    u.x = f2bf(v.x); u.y = f2bf(v.y); u.z = f2bf(v.z); u.w = f2bf(v.w);
    *(ushort4*)dst = u;
  }
}

// ---------------- kernel 2: QKV projection GEMM ----------------------------
// C[m][n] = sum_k X[m][k] * W[n][k]  (+bias). z=0:Q (scaled /8*log2e, [b,h,s,d])
// z=1:K ([b,h,s,d]), z=2:V transposed ([b,h,d,s]) via swapped operand roles.
#define GBM 128
#define GBN 128
#define GBK 64

__global__ __launch_bounds__(256) void qkv_gemm(
    const unsigned short* __restrict__ Xbf,
    const unsigned short* __restrict__ Wbf,
    const float* __restrict__ bq, const float* __restrict__ bk,
    const float* __restrict__ bv,
    unsigned short* __restrict__ Qo, unsigned short* __restrict__ Ko,
    unsigned short* __restrict__ Vt) {
  __shared__ char lds[GBM * GBK * 2 * 2];   // A 16KB + B 16KB
  char* ldsA = lds;
  char* ldsB = lds + GBM * GBK * 2;

  const int tid = threadIdx.x;
  const int w = tid >> 6;
  const int l = tid & 63;
  const int z = blockIdx.z;
  const int mtile = blockIdx.x * GBM;
  const int ntile = blockIdx.y * GBN;
  const int wm = w >> 1, wn = w & 1;
  const int lrow = l & 15, lgrp = l >> 4;

  const unsigned short* Wz = Wbf + (long long)z * H_ * H_;

  f32x4 acc[4][4];
  f32x4 zero = {0.f, 0.f, 0.f, 0.f};
  #pragma unroll
  for (int i = 0; i < 4; ++i)
    #pragma unroll
    for (int j = 0; j < 4; ++j) acc[i][j] = zero;

  for (int kt = 0; kt < H_ / GBK; ++kt) {
    const int k0 = kt * GBK;
    #pragma unroll
    for (int t = 0; t < 4; ++t) {
      int j = w * 4 + t;                       // 0..15, wave-uniform
      int row = j * 8 + (l >> 3);
      int so = ((l & 7) ^ (row & 7)) * 8;
      gld_lds16(ldsA + j * 1024, Xbf + (long long)(mtile + row) * H_ + k0 + so);
      gld_lds16(ldsB + j * 1024, Wz  + (long long)(ntile + row) * H_ + k0 + so);
    }
    __syncthreads();

    char* srcA = (z == 2) ? ldsB : ldsA;      // z==2: swap roles so C rows = d
    char* srcB = (z == 2) ? ldsA : ldsB;
    const int wA = (z == 2) ? wn : wm;
    const int wB = (z == 2) ? wm : wn;

    short8 af[4][2], bf[4][2];
    #pragma unroll
    for (int ib = 0; ib < 4; ++ib)
      #pragma unroll
      for (int ks = 0; ks < 2; ++ks) {
        int rA = wA * 64 + ib * 16 + lrow;
        af[ib][ks] = *(const short8*)(srcA + rA * 128 + (((ks * 4 + lgrp) ^ (rA & 7)) * 16));
        int rB = wB * 64 + ib * 16 + lrow;
        bf[ib][ks] = *(const short8*)(srcB + rB * 128 + (((ks * 4 + lgrp) ^ (rB & 7)) * 16));
      }
    #pragma unroll
    for (int ib = 0; ib < 4; ++ib)
      #pragma unroll
      for (int jb = 0; jb < 4; ++jb)
        #pragma unroll
        for (int ks = 0; ks < 2; ++ks)
          acc[ib][jb] = __builtin_amdgcn_mfma_f32_16x16x32_bf16(
              af[ib][ks], bf[jb][ks], acc[ib][jb], 0, 0, 0);
    __syncthreads();
  }

  const float* bias = (z == 0) ? bq : (z == 1) ? bk : bv;
  if (z != 2) {
    unsigned short* O = (z == 0) ? Qo : Ko;
    #pragma unroll
    for (int jb = 0; jb < 4; ++jb) {
      int n = ntile + wn * 64 + jb * 16 + lrow;
      float bv_ = bias[n];
      int h = n >> 6, d = n & 63;
      #pragma unroll
      for (int ib = 0; ib < 4; ++ib)
        #pragma unroll
        for (int r = 0; r < 4; ++r) {
          int m = mtile + wm * 64 + ib * 16 + lgrp * 4 + r;
          float val = acc[ib][jb][r] + bv_;
          if (z == 0) val *= 0.125f * LOG2E;   // fold 1/sqrt(64) * log2(e) into Q
          int b = m >> 10, s = m & 1023;
          O[(((long long)(b * NH_ + h)) * S_ + s) * D_ + d] = f2bf(val);
        }
    }
  } else {
    #pragma unroll
    for (int ib = 0; ib < 4; ++ib)
      #pragma unroll
      for (int r = 0; r < 4; ++r) {
        int n = ntile + wn * 64 + ib * 16 + lgrp * 4 + r;   // d-side (C row)
        float bv_ = bias[n];
        int h = n >> 6, d = n & 63;
        #pragma unroll
        for (int jb = 0; jb < 4; ++jb) {
          int m = mtile + wm * 64 + jb * 16 + lrow;          // s-side (C col)
          float val = acc[ib][jb][r] + bv_;
          int b = m >> 10, s = m & 1023;
          Vt[(((long long)(b * NH_ + h)) * D_ + d) * S_ + s] = f2bf(val);
        }
      }
  }
}

// ---------------- kernel 3: fused flash attention (32x32 swapped) ----------
// block = 4 waves, each wave owns 64 q rows (block = 256 q). KVBLK = 64.
// QK^T swapped: S^T = mfma(K, Q)  -> lane owns q-column (l&31), keys in regs.
// PV  swapped: O^T = mfma(V^T, P^T) -> softmax state & epilogue lane-local.
__global__ __launch_bounds__(256, 2) void attn_fused(
    const unsigned short* __restrict__ Qbf,
    const unsigned short* __restrict__ Kbf,
    const unsigned short* __restrict__ Vtb,
    const float* __restrict__ mask,
    float* __restrict__ out) {
  __shared__ char lds[32768];                 // 2 x (K 8KB | V^T 8KB)
  const int tid = threadIdx.x, w = tid >> 6, l = tid & 63;
  const int l31 = l & 31, h = l >> 5;

  // bijective XCD-grouping: the 4 q-tiles of one bh land on the same XCD
  const int lid = blockIdx.x;                 // 0..511
  const int xcd = lid & 7, k8 = lid >> 3;
  const int bh = xcd * 16 + (k8 >> 2);
  const int qt = k8 & 3;
  const int b = bh >> 4, hd = bh & 15;
  const int q0 = qt * 256 + w * 64;

  const unsigned short* Kg = Kbf + (long long)bh * S_ * D_;
  const unsigned short* Vg = Vtb + (long long)bh * D_ * S_;
  const float* mrow = mask + b * S_;

  // stage tile 0 ASAP
  {
    const int row = (w * 2) * 8 + (l >> 3);   // t=0
    const int row1 = (w * 2 + 1) * 8 + (l >> 3);
    const int so = ((l & 7) ^ (row & 7)) * 8;
    const int so1 = ((l & 7) ^ (row1 & 7)) * 8;
    gld_lds16(lds + (w * 2) * 1024,        Kg + (long long)row * D_ + so);
    gld_lds16(lds + (w * 2 + 1) * 1024,    Kg + (long long)row1 * D_ + so1);
    gld_lds16(lds + 8192 + (w * 2) * 1024, Vg + (long long)row * S_ + so);
    gld_lds16(lds + 8192 + (w * 2 + 1) * 1024, Vg + (long long)row1 * S_ + so1);
  }

  // Q fragments: qf[qb][ks] = Q[q0+qb*32+l31][ks*16+8h .. +7]
  short8 qf[2][4];
  #pragma unroll
  for (int qb = 0; qb < 2; ++qb)
    #pragma unroll
    for (int ks = 0; ks < 4; ++ks)
      qf[qb][ks] = *(const short8*)(Qbf + ((long long)bh * S_ + q0 + qb * 32 + l31) * D_ + ks * 16 + 8 * h);

  f32x16 acc[2][2];
  #pragma unroll
  for (int db = 0; db < 2; ++db)
    #pragma unroll
    for (int qb = 0; qb < 2; ++qb)
      #pragma unroll
      for (int r = 0; r < 16; ++r) acc[db][qb][r] = 0.f;
  float m_run[2] = {-1e30f, -1e30f};
  float l_run[2] = {0.f, 0.f};

  __syncthreads();

  for (int kt = 0; kt < S_ / 64; ++kt) {
    const int p = kt & 1;
    char* ldsK = lds + p * 16384;
    char* ldsV = ldsK + 8192;
    const int key0 = kt * 64;

    // prefetch next tile into other buffer
    if (kt < S_ / 64 - 1) {
      char* nb = lds + (p ^ 1) * 16384;
      const int nk0 = key0 + 64;
      #pragma unroll
      for (int t = 0; t < 2; ++t) {
        int j = w * 2 + t;
        int row = j * 8 + (l >> 3);
        int so = ((l & 7) ^ (row & 7)) * 8;
        gld_lds16(nb + j * 1024,        Kg + (long long)(nk0 + row) * D_ + so);
        gld_lds16(nb + 8192 + j * 1024, Vg + (long long)row * S_ + nk0 + so);
      }
    }

    // ---- QK^T (swapped): sc[kb][qb] = S^T[key 32-block][q 32-block]
    f32x16 sc[2][2];
    #pragma unroll
    for (int kb = 0; kb < 2; ++kb)
      #pragma unroll
      for (int qb = 0; qb < 2; ++qb)
        #pragma unroll
        for (int r = 0; r < 16; ++r) sc[kb][qb][r] = 0.f;

    #pragma unroll
    for (int kb = 0; kb < 2; ++kb) {
      short8 kf[4];
      #pragma unroll
      for (int ks = 0; ks < 4; ++ks) {
        int row = kb * 32 + l31;
        int g = (2 * ks + h) ^ (row & 7);
        kf[ks] = *(const short8*)(ldsK + row * 128 + g * 16);
      }
      __builtin_amdgcn_s_setprio(1);
      #pragma unroll
      for (int qb = 0; qb < 2; ++qb)
        #pragma unroll
        for (int ks = 0; ks < 4; ++ks)
          sc[kb][qb] = __builtin_amdgcn_mfma_f32_32x32x16_bf16(
              kf[ks], qf[qb][ks], sc[kb][qb], 0, 0, 0);
      __builtin_amdgcn_s_setprio(0);
    }

    // ---- softmax per q-block (lane owns q = l&31 entirely; h halves mirror)
    short8 pfrag[2][4];
    #pragma unroll
    for (int qb = 0; qb < 2; ++qb) {
      float sv[32];
      #pragma unroll
      for (int kb = 0; kb < 2; ++kb)
        #pragma unroll
        for (int rg = 0; rg < 4; ++rg) {
          f32x4 m4 = *(const f32x4*)(mrow + key0 + kb * 32 + rg * 8 + 4 * h);
          #pragma unroll
          for (int c = 0; c < 4; ++c)
            sv[kb * 16 + rg * 4 + c] = fmaf(m4[c], LOG2E, sc[kb][qb][rg * 4 + c]);
        }
      // max tree (log2 domain scores)
      float r16[16];
      #pragma unroll
      for (int i = 0; i < 16; ++i) r16[i] = fmaxf(sv[i], sv[i + 16]);
      #pragma unroll
      for (int i = 0; i < 8; ++i) r16[i] = fmaxf(r16[i], r16[i + 8]);
      #pragma unroll
      for (int i = 0; i < 4; ++i) r16[i] = fmaxf(r16[i], r16[i + 4]);
      float pm = fmaxf(fmaxf(r16[0], r16[1]), fmaxf(r16[2], r16[3]));
      pm = fmaxf(pm, __shfl_xor(pm, 32));
      // defer-max (T13): only rescale when the running max grows materially
      if (!__all(pm - m_run[qb] <= 11.5f)) {
        float mn = fmaxf(m_run[qb], pm);
        float rs = EXP2(m_run[qb] - mn);
        m_run[qb] = mn;
        l_run[qb] *= rs;
        #pragma unroll
        for (int db = 0; db < 2; ++db)
          #pragma unroll
          for (int r = 0; r < 16; ++r) acc[db][qb][r] *= rs;
      }
      const float mcur = m_run[qb];
      #pragma unroll
      for (int i = 0; i < 32; ++i) sv[i] = EXP2(sv[i] - mcur);
      // sum tree
      #pragma unroll
      for (int i = 0; i < 16; ++i) r16[i] = sv[i] + sv[i + 16];
      #pragma unroll
      for (int i = 0; i < 8; ++i) r16[i] = r16[i] + r16[i + 8];
      #pragma unroll
      for (int i = 0; i < 4; ++i) r16[i] = r16[i] + r16[i + 4];
      float ps = (r16[0] + r16[1]) + (r16[2] + r16[3]);
      ps += __shfl_xor(ps, 32);
      l_run[qb] += ps;

      // pack P to bf16 pairs: Wd[j] = keys {8j+4h+0..3} at col q
      unsigned Wd[8][2];
      #pragma unroll
      for (int j = 0; j < 8; ++j) {
        int base = (j >> 2) * 16 + (j & 3) * 4;
        asm("v_cvt_pk_bf16_f32 %0, %1, %2" : "=v"(Wd[j][0]) : "v"(sv[base + 0]), "v"(sv[base + 1]));
        asm("v_cvt_pk_bf16_f32 %0, %1, %2" : "=v"(Wd[j][1]) : "v"(sv[base + 2]), "v"(sv[base + 3]));
      }
      // half-exchange: B-frag(ks) = keys 16ks+8h+0..7 at col q
      #pragma unroll
      for (int ks = 0; ks < 4; ++ks) {
        unsigned s0 = h ? Wd[2 * ks][0] : Wd[2 * ks + 1][0];
        unsigned s1 = h ? Wd[2 * ks][1] : Wd[2 * ks + 1][1];
        unsigned r0 = __shfl_xor(s0, 32);
        unsigned r1 = __shfl_xor(s1, 32);
        unsigned o0 = h ? Wd[2 * ks + 1][0] : Wd[2 * ks][0];
        unsigned o1 = h ? Wd[2 * ks + 1][1] : Wd[2 * ks][1];
        union { unsigned u[4]; short8 s; } fu;
        fu.u[0] = h ? r0 : o0;
        fu.u[1] = h ? r1 : o1;
        fu.u[2] = h ? o0 : r0;
        fu.u[3] = h ? o1 : r1;
        pfrag[qb][ks] = fu.s;
      }
    }

    // ---- PV (swapped): acc[db][qb] += V^T-frag x P^T-frag
    #pragma unroll
    for (int db = 0; db < 2; ++db) {
      short8 vf[4];
      #pragma unroll
      for (int ks = 0; ks < 4; ++ks) {
        int row = db * 32 + l31;
        int g = (2 * ks + h) ^ (row & 7);
        vf[ks] = *(const short8*)(ldsV + row * 128 + g * 16);
      }
      __builtin_amdgcn_s_setprio(1);
      #pragma unroll
      for (int qb = 0; qb < 2; ++qb)
        #pragma unroll
        for (int ks = 0; ks < 4; ++ks)
          acc[db][qb] = __builtin_amdgcn_mfma_f32_32x32x16_bf16(
              vf[ks], pfrag[qb][ks], acc[db][qb], 0, 0, 0);
      __builtin_amdgcn_s_setprio(0);
    }

    __syncthreads();   // drains vmcnt (stage) + lgkm; flips buffers
  }

  // ---- epilogue: out[b, s=q, hd*64 + d] = acc^T / l_run  (float4 stores)
  #pragma unroll
  for (int qb = 0; qb < 2; ++qb) {
    float inv = 1.0f / l_run[qb];
    int q = q0 + qb * 32 + l31;
    float* orow = out + ((long long)b * S_ + q) * H_ + hd * D_;
    #pragma unroll
    for (int db = 0; db < 2; ++db)
      #pragma unroll
      for (int rg = 0; rg < 4; ++rg) {
        f32x4 v4;
        #pragma unroll
        for (int c = 0; c < 4; ++c) v4[c] = acc[db][qb][rg * 4 + c] * inv;
        *(f32x4*)(orow + db * 32 + rg * 8 + 4 * h) = v4;
      }
  }
}

// ---------------- launcher -------------------------------------------------
extern "C" void kernel_launch(void* const* d_in, const int* in_sizes, int n_in,
                              void* d_out, int out_size, void* d_ws, size_t ws_size,
                              hipStream_t stream) {
  const float* X    = (const float*)d_in[0];
  const float* mask = (const float*)d_in[1];
  const float* Wq   = (const float*)d_in[2];
  const float* bq   = (const float*)d_in[3];
  const float* Wk   = (const float*)d_in[4];
  const float* bk   = (const float*)d_in[5];
  const float* Wv   = (const float*)d_in[6];
  const float* bv   = (const float*)d_in[7];
  float* out = (float*)d_out;

  char* ws = (char*)d_ws;
  unsigned short* Xbf = (unsigned short*)ws;                 // 16 MB
  unsigned short* Wbf = (unsigned short*)(ws + 16777216);    //  6 MB
  unsigned short* Qb  = (unsigned short*)(ws + 23068672);    // 16 MB
  unsigned short* Kb  = (unsigned short*)(ws + 39845888);    // 16 MB
  unsigned short* Vt  = (unsigned short*)(ws + 56623104);    // 16 MB

  hipLaunchKernelGGL(cvt_f32_bf16, dim3(2048), dim3(256), 0, stream,
                     X, Wq, Wk, Wv, Xbf, Wbf);
  hipLaunchKernelGGL(qkv_gemm, dim3(M_TOT / GBM, H_ / GBN, 3), dim3(256), 0, stream,
                     Xbf, Wbf, bq, bk, bv, Qb, Kb, Vt);
  hipLaunchKernelGGL(attn_fused, dim3(512), dim3(256), 0, stream,
                     Qb, Kb, Vt, mask, out);
}